// Round 5
// baseline (206.047 us; speedup 1.0000x reference)
//
#include <hip/hip_runtime.h>

// GCN 2-layer forward, fp32 in/out, fp16 gather tables. Build: 2-pass MSD
// radix sort by target node -> PADDED CSR: each node's srcs padded to a
// multiple of 16 PLUS one 16-entry dummy block (index n -> zeroed table
// row); global dummy block at srcs[0..15] for zero-degree nodes (pse=(0,0)).
// Aggregate: one wave per TWO nodes, 16 lanes per 32 B fp16 row, int4 srcs
// loads (1 per node per block-step), 3-deep gather rotation -> 16 gather
// insts in flight at the consume-wait. XCD pass-pinning on fused layer-1:
// lo-table blocks on XCDs 0-3, hi on 4-7 (each XCD's table fits 4 MiB L2).
// History: r12 fp16 tables; r13 tail-split regressed (latency not VALU);
// r14 split tables FETCH 101->29/pass, time flat (4-deep only); r15 2-blk
// rotation; r16 2 nodes/wave + fused lo/hi (53.8us, 3 HBM misses/step
// exposed); r17 (this): 3-deep + int4 srcs + dummy blocks + XCD pinning.

#define WAVE 64
#define BN2 512           // nodes per bucket (9 bits local col)
#define NBMAX 256         // max coarse buckets (N <= 131072)
#define CHUNK 8192        // edges per partition block

typedef _Float16 f16;

// ---- bucket count: global histogram of col>>9 ----
__global__ void bucket_count_kernel(const int* __restrict__ col, int* __restrict__ gcnt,
                                    int E, int nb) {
    __shared__ int h[NBMAX];
    for (int i = threadIdx.x; i < nb; i += blockDim.x) h[i] = 0;
    __syncthreads();
    for (int e = blockIdx.x * blockDim.x + threadIdx.x; e < E; e += gridDim.x * blockDim.x)
        atomicAdd(&h[col[e] >> 9], 1);
    __syncthreads();
    for (int i = threadIdx.x; i < nb; i += blockDim.x)
        if (h[i]) atomicAdd(&gcnt[i], h[i]);
}

// ---- exclusive scan of bucket counts -> bptr[nb+1]; init gcursor; init
//      gpcur=16 (slot 0..15 = global dummy block); fill global dummy srcs;
//      zero the dummy gather rows (row N of each fp16 table) ----
__global__ void bucket_scan_kernel(const int* __restrict__ cnt, int* __restrict__ bptr,
                                   int* __restrict__ gcur, int nb, int* __restrict__ gpcur,
                                   int* __restrict__ srcs,
                                   f16* __restrict__ hlo, f16* __restrict__ hhi,
                                   f16* __restrict__ h2t, int nzr) {
    int lane = threadIdx.x;  // single wave
    if (lane == 0) gpcur[0] = 16;
    if (lane < 16) srcs[lane] = nzr;              // global dummy block
    if (lane < 16)      hlo[(size_t)nzr * 16 + lane]        = (f16)0.f;
    else if (lane < 32) hhi[(size_t)nzr * 16 + (lane - 16)] = (f16)0.f;
    else if (lane < 48) h2t[(size_t)nzr * 16 + (lane - 32)] = (f16)0.f;
    int carry = 0;
    for (int base = 0; base < nb; base += WAVE) {
        int i = base + lane;
        int orig = (i < nb) ? cnt[i] : 0;
        int v = orig;
#pragma unroll
        for (int off = 1; off < WAVE; off <<= 1) {
            int t = __shfl_up(v, off, WAVE);
            if (lane >= off) v += t;
        }
        if (i < nb) { bptr[i] = carry + v - orig; gcur[i] = carry + v - orig; }
        carry += __shfl(v, WAVE - 1, WAVE);
    }
    if (lane == 0) bptr[nb] = carry;
}

// ---- pass 1: LDS-binned partition of packed (src<<9 | local_col) ----
__global__ void __launch_bounds__(512)
partition_kernel(const int* __restrict__ row, const int* __restrict__ col,
                 int* __restrict__ gcursor, unsigned* __restrict__ packed,
                 int E, int nb) {
    __shared__ int hist[NBMAX], excl[NBMAX], cursor[NBMAX], baseoff[NBMAX];
    __shared__ unsigned stage[CHUNK];
    int chunk0 = blockIdx.x * CHUNK;
    int cn = E - chunk0; if (cn > CHUNK) cn = CHUNK;
    for (int i = threadIdx.x; i < nb; i += blockDim.x) hist[i] = 0;
    __syncthreads();
    for (int i = threadIdx.x; i < cn; i += blockDim.x)
        atomicAdd(&hist[col[chunk0 + i] >> 9], 1);
    __syncthreads();
    if (threadIdx.x < WAVE) {
        int lane = threadIdx.x, carry = 0;
        for (int base = 0; base < nb; base += WAVE) {
            int i = base + lane;
            int orig = (i < nb) ? hist[i] : 0;
            int v = orig;
#pragma unroll
            for (int off = 1; off < WAVE; off <<= 1) {
                int t = __shfl_up(v, off, WAVE);
                if (lane >= off) v += t;
            }
            if (i < nb) { excl[i] = carry + v - orig; cursor[i] = carry + v - orig; }
            carry += __shfl(v, WAVE - 1, WAVE);
        }
    }
    __syncthreads();
    for (int b = threadIdx.x; b < nb; b += blockDim.x) {
        int c = hist[b];
        baseoff[b] = c ? atomicAdd(&gcursor[b], c) : 0;
    }
    __syncthreads();
    for (int i = threadIdx.x; i < cn; i += blockDim.x) {
        int c = col[chunk0 + i], r = row[chunk0 + i];
        int b = c >> 9;
        int pos = atomicAdd(&cursor[b], 1);
        stage[pos] = ((unsigned)r << 9) | (unsigned)(c & (BN2 - 1));
    }
    __syncthreads();
    int wave = threadIdx.x >> 6, lane = threadIdx.x & 63, nw = blockDim.x >> 6;
    for (int b = wave; b < nb; b += nw) {
        int c = hist[b]; if (!c) continue;
        int s = excl[b], d = baseoff[b];
        for (int k = lane; k < c; k += WAVE) packed[d + k] = stage[s + k];
    }
}

// ---- pass 2: per-bucket sort by local node -> padded srcs, pse, dinv.
//      Region = pad16(d) + 16-entry dummy block (all = n). Zero-degree
//      nodes get pse=(0,0) -> global dummy block. ----
__global__ void __launch_bounds__(512)
sort_kernel(const int* __restrict__ bptr, const unsigned* __restrict__ packed,
            int* __restrict__ srcs, int2* __restrict__ pse,
            float* __restrict__ dinv, int* __restrict__ gpcur,
            int n, int nb, int E) {
    __shared__ int hist[BN2], pex[BN2], cur[BN2];
    __shared__ int pbase_s;
    int b = blockIdx.x;
    int start = bptr[b], end = bptr[b + 1];
    for (int i = threadIdx.x; i < BN2; i += blockDim.x) { hist[i] = 0; cur[i] = 0; }
    __syncthreads();
    for (int k = start + threadIdx.x; k < end; k += blockDim.x)
        atomicAdd(&hist[packed[k] & (BN2 - 1)], 1);
    __syncthreads();
    if (threadIdx.x < WAVE) {   // scan of region sizes over 512 locals
        int lane = threadIdx.x, carry = 0;
#pragma unroll
        for (int base = 0; base < BN2; base += WAVE) {
            int i = base + lane;
            int d = hist[i];
            int rg = d ? (((d + 15) & ~15) + 16) : 0;
            int v = rg;
#pragma unroll
            for (int off = 1; off < WAVE; off <<= 1) {
                int t = __shfl_up(v, off, WAVE);
                if (lane >= off) v += t;
            }
            pex[i] = carry + v - rg;
            carry += __shfl(v, WAVE - 1, WAVE);
        }
        if (lane == 0) pbase_s = atomicAdd(gpcur, carry);
    }
    __syncthreads();
    int pbase = pbase_s;
    for (int i = threadIdx.x; i < BN2; i += blockDim.x) {
        int node = b * BN2 + i;
        if (node < n) {
            int d = hist[i];
            int pd = (d + 15) & ~15;
            int ps = pbase + pex[i];
            pse[node]  = d ? make_int2(ps, ps + pd) : make_int2(0, 0);
            dinv[node] = d ? rsqrtf((float)d) : 0.f;
            if (d) for (int k = d; k < pd + 16; ++k) srcs[ps + k] = n;  // pads + dummy block
        }
    }
    __syncthreads();
    for (int k = start + threadIdx.x; k < end; k += blockDim.x) {
        unsigned p = packed[k];
        int lc = p & (BN2 - 1);
        int pos = atomicAdd(&cur[lc], 1);
        srcs[pbase + pex[lc] + pos] = (int)(p >> 9);
    }
}

// ---- dense: h[n,OUTC] = fp16( (x[n,INC] @ W) * dinv[n] ).
//      Thread = 2 nodes x 4 j. W^T in LDS, stride INC+4 (conflict-free).
//      SPLIT: route cols 0-15 -> hlo, 16-31 -> hhi (16-wide fp16 rows). ----
template <int INC, int OUTC, int JT, bool SPLIT>
__global__ void __launch_bounds__(256, 4)
dense_kernel(const float* __restrict__ x, const float* __restrict__ W,
             const float* __restrict__ dinv, f16* __restrict__ hlo,
             f16* __restrict__ hhi, int n) {
    const int LSTR = INC + 4;
    const int SP   = 256 / JT;     // node slots (pairs) per block
    const int NT   = SP * 2;       // nodes per block
    __shared__ float Wt[OUTC * LSTR];
    for (int i = threadIdx.x; i < INC * OUTC; i += 256) {
        int k = i / OUTC, j = i % OUTC;
        Wt[j * LSTR + k] = W[i];
    }
    __syncthreads();
    const int jg = threadIdx.x % JT;
    const int sp = threadIdx.x / JT;
    int base = blockIdx.x * NT;
    int n0 = base + sp;
    int n1 = base + sp + SP;
    int n0c = n0 < n ? n0 : n - 1;   // clamp reads, guard writes
    int n1c = n1 < n ? n1 : n - 1;
    const float4* xr0 = (const float4*)(x + (size_t)n0c * INC);
    const float4* xr1 = (const float4*)(x + (size_t)n1c * INC);
    float a[2][4] = {{0.f, 0.f, 0.f, 0.f}, {0.f, 0.f, 0.f, 0.f}};
#pragma unroll 4
    for (int k4 = 0; k4 < INC / 4; ++k4) {
        float4 v0 = xr0[k4];
        float4 v1 = xr1[k4];
#pragma unroll
        for (int u = 0; u < 4; ++u) {
            float4 w = *(const float4*)(Wt + (jg + u * JT) * LSTR + 4 * k4);
            a[0][u] = fmaf(v0.x, w.x, fmaf(v0.y, w.y, fmaf(v0.z, w.z, fmaf(v0.w, w.w, a[0][u]))));
            a[1][u] = fmaf(v1.x, w.x, fmaf(v1.y, w.y, fmaf(v1.z, w.z, fmaf(v1.w, w.w, a[1][u]))));
        }
    }
#pragma unroll
    for (int pair = 0; pair < 2; ++pair) {
        int nn = pair ? n1 : n0;
        if (nn < n) {
            float d = dinv[nn];
#pragma unroll
            for (int u = 0; u < 4; ++u) {
                int c = jg + u * JT;
                f16* t;
                if (SPLIT) t = (c < 16) ? (hlo + (size_t)nn * 16 + c)
                               : (hhi + (size_t)nn * 16 + (c - 16));
                else       t = hlo + (size_t)nn * OUTC + c;
                *t = (f16)(a[pair][u] * d);
            }
        }
    }
}

// ---- aggregate: one wave per TWO nodes; 16 lanes per 32 B fp16 row.
//      Per block-step per node: 1 int4 srcs load + 4 gather insts.
//      3-deep rotation: at the consume-wait, 16 gather insts + 2 srcs
//      in flight. All clamped reads land on dummy blocks / zero row.
//      PIN: bijective XCD swizzle -> lo pass on XCDs 0-3, hi on 4-7. ----
#define GLD(s) (*(const f16*)(hb + (((unsigned)(s) << 5) + j2)))
#define IDX0(t) (((((t) < nb0) ? (t) : nb0) << 2) + eo)
#define IDX1(t) (((((t) < nb1) ? (t) : nb1) << 2) + eo)

template <bool RELU, bool PIN>
__global__ void __launch_bounds__(256)
csr_agg16x2_kernel(const int2* __restrict__ pse, const int* __restrict__ srcs,
                   const float* __restrict__ dinv, const f16* __restrict__ tlo,
                   const f16* __restrict__ thi, const float* __restrict__ bias,
                   float* __restrict__ out, int ostride, int hg, int n, int tailidx) {
    int bid = blockIdx.x;
    if (PIN) {
        int per = (hg * 2) >> 3;             // blocks per XCD (grid % 8 == 0)
        bid = (bid & 7) * per + (bid >> 3);  // XCD 0-3 -> lo, 4-7 -> hi
    }
    int pass = (bid >= hg) ? 1 : 0;
    const f16* hs = pass ? thi : tlo;
    int ocol = pass << 4;
    int bip = bid - pass * hg;
    int lane = threadIdx.x & 63;
    int wid  = threadIdx.x >> 6;
    int j  = lane & 15;
    int eo = lane >> 4;           // 0..3
    if (tailidx >= 0 && blockIdx.x == 0 && threadIdx.x == 0) out[tailidx] = 0.f;
    int n0 = (bip * 4 + wid) * 2;
    if (n0 >= n) return;
    int n1 = n0 + 1;
    bool v1 = n1 < n;
    int4 se = *(const int4*)(pse + n0);      // pse[n0], pse[n1]
    int nb0 = (se.y - se.x) >> 4;
    int nb1 = v1 ? ((se.w - se.z) >> 4) : 0;
    float dv0 = dinv[n0];
    float dv1 = v1 ? dinv[n1] : 0.f;
    float bj = bias[ocol + j];
    size_t ob0 = (size_t)n0 * ostride + ocol + j;
    size_t ob1 = (size_t)n1 * ostride + ocol + j;
    int MAXB = nb0 > nb1 ? nb0 : nb1;
    if (MAXB == 0) {
        float v = bj;
        if (RELU) v = v > 0.f ? v : 0.f;
        if (eo == 0) out[ob0] = v;
        else if (eo == 1 && v1) out[ob1] = v;
        return;
    }
    const unsigned j2 = (unsigned)(j << 1);
    const char* hb = (const char*)hs;
    const int4* P0 = (const int4*)(srcs + se.x);
    const int4* P1 = (const int4*)(srcs + (v1 ? se.z : se.x));
    if (!v1) nb1 = 0;  // (already 0; clamp to node0's block 0 is harmless, unused)
    // prologue: srcs for blocks 0,1,2; gathers for blocks 0,1
    int4 sA0 = P0[IDX0(0)], sA1 = P1[IDX1(0)];
    int4 sB0 = P0[IDX0(1)], sB1 = P1[IDX1(1)];
    int4 sC0 = P0[IDX0(2)], sC1 = P1[IDX1(2)];
    f16 a0 = GLD(sA0.x), a1 = GLD(sA0.y), a2 = GLD(sA0.z), a3 = GLD(sA0.w);
    f16 a4 = GLD(sA1.x), a5 = GLD(sA1.y), a6 = GLD(sA1.z), a7 = GLD(sA1.w);
    f16 e0 = GLD(sB0.x), e1 = GLD(sB0.y), e2 = GLD(sB0.z), e3 = GLD(sB0.w);
    f16 e4 = GLD(sB1.x), e5 = GLD(sB1.y), e6 = GLD(sB1.z), e7 = GLD(sB1.w);
    float acc0 = 0.f, acc1 = 0.f, acc2 = 0.f, acc3 = 0.f;
    for (int t = 0; t < MAXB; ++t) {
        // issue gathers for block t+2 (from sC), srcs for block t+3
        f16 g0 = GLD(sC0.x), g1 = GLD(sC0.y), g2 = GLD(sC0.z), g3 = GLD(sC0.w);
        f16 g4 = GLD(sC1.x), g5 = GLD(sC1.y), g6 = GLD(sC1.z), g7 = GLD(sC1.w);
        int4 sD0 = P0[IDX0(t + 3)], sD1 = P1[IDX1(t + 3)];
        // consume block t (waits only the oldest 8 gathers)
        acc0 += (float)a0; acc1 += (float)a1;
        acc0 += (float)a2; acc1 += (float)a3;
        acc2 += (float)a4; acc3 += (float)a5;
        acc2 += (float)a6; acc3 += (float)a7;
        a0 = e0; a1 = e1; a2 = e2; a3 = e3;
        a4 = e4; a5 = e5; a6 = e6; a7 = e7;
        e0 = g0; e1 = g1; e2 = g2; e3 = g3;
        e4 = g4; e5 = g5; e6 = g6; e7 = g7;
        sC0 = sD0; sC1 = sD1;
    }
    float accA = acc0 + acc1;  // node0
    float accB = acc2 + acc3;  // node1
    accA += __shfl_xor(accA, 16, WAVE);
    accA += __shfl_xor(accA, 32, WAVE);
    accB += __shfl_xor(accB, 16, WAVE);
    accB += __shfl_xor(accB, 32, WAVE);
    if (eo == 0) {
        float v = accA * dv0 + bj;
        if (RELU) v = v > 0.f ? v : 0.f;
        out[ob0] = v;
    } else if (eo == 1 && v1) {
        float v = accB * dv1 + bj;
        if (RELU) v = v > 0.f ? v : 0.f;
        out[ob1] = v;
    }
}

extern "C" void kernel_launch(void* const* d_in, const int* in_sizes, int n_in,
                              void* d_out, int out_size, void* d_ws, size_t ws_size,
                              hipStream_t stream) {
    const float* x  = (const float*)d_in[0];
    const int*   ei = (const int*)d_in[1];    // harness converts int64 -> int32
    const float* W1 = (const float*)d_in[2];
    const float* b1 = (const float*)d_in[3];
    const float* W2 = (const float*)d_in[4];
    const float* b2 = (const float*)d_in[5];

    const int IN_C = 128, HID = 32, OC = 16;
    const int N = in_sizes[0] / IN_C;       // 100000
    const int E = in_sizes[1] / 2;          // 3200000
    const int* row = ei;
    const int* col = ei + E;
    const int NB = (N + BN2 - 1) / BN2;     // 196 coarse buckets

    char* base = (char*)d_ws;
    size_t off = 0;
    auto carve = [&](size_t bytes) -> char* {
        char* p = base + off;
        off = (off + bytes + 255) & ~(size_t)255;
        return p;
    };
    int*      gcnt  = (int*)     carve((size_t)NB * 4);
    int*      bptr  = (int*)     carve((size_t)(NB + 1) * 4);
    int*      gcur  = (int*)     carve((size_t)NB * 4);
    int*      gpcur = (int*)     carve(8);
    float*    dinv  = (float*)   carve((size_t)N * 4);
    int2*     pse   = (int2*)    carve((size_t)(N + 2) * 8);
    unsigned* packed= (unsigned*)carve((size_t)E * 4);
    int*      srcsP = (int*)     carve(((size_t)E + (size_t)N * 32 + 256) * 4); // pads + dummy blocks
    f16*      hlo   = (f16*)     carve((size_t)(N + 1) * 16 * 2);  // layer1 cols 0-15 (+zero row)
    f16*      hhi   = (f16*)     carve((size_t)(N + 1) * 16 * 2);  // layer1 cols 16-31
    f16*      h2t   = (f16*)     carve((size_t)(N + 1) * 16 * 2);  // layer2 table
    float*    bufB  = (float*)   carve((size_t)N * HID * 4);       // relu(agg1), fp32
    (void)ws_size; (void)n_in;

    float* outp = (float*)d_out;

    // build: 2-pass coarse radix sort by target node -> padded CSR + dinv
    hipMemsetAsync(gcnt, 0, (size_t)NB * 4, stream);
    bucket_count_kernel<<<512, 256, 0, stream>>>(col, gcnt, E, NB);
    bucket_scan_kernel<<<1, 64, 0, stream>>>(gcnt, bptr, gcur, NB, gpcur, srcsP, hlo, hhi, h2t, N);
    partition_kernel<<<(E + CHUNK - 1) / CHUNK, 512, 0, stream>>>(row, col, gcur, packed, E, NB);
    sort_kernel<<<NB, 512, 0, stream>>>(bptr, packed, srcsP, pse, dinv, gpcur, N, NB, E);

    int npb = 8;                         // 4 waves x 2 nodes per block
    int g2  = (N + npb - 1) / npb;       // 12500 blocks per pass

    // layer 1: {hlo,hhi} = fp16((x@W1)*dinv) ; bufB = relu(dinv*agg + b1)
    {
        const int NT = (256 / 8) * 2;  // 64 nodes per block
        dense_kernel<128, 32, 8, true><<<(N + NT - 1) / NT, 256, 0, stream>>>(x, W1, dinv, hlo, hhi, N);
        if (((2 * g2) & 7) == 0)
            csr_agg16x2_kernel<true, true><<<2 * g2, 256, 0, stream>>>(
                pse, srcsP, dinv, hlo, hhi, b1, bufB, HID, g2, N, -1);
        else
            csr_agg16x2_kernel<true, false><<<2 * g2, 256, 0, stream>>>(
                pse, srcsP, dinv, hlo, hhi, b1, bufB, HID, g2, N, -1);
    }
    // layer 2: h2t = fp16((bufB@W2)*dinv) ; out = dinv*agg(h2t) + b2
    {
        const int NT = (256 / 4) * 2;  // 128 nodes per block
        dense_kernel<32, 16, 4, false><<<(N + NT - 1) / NT, 256, 0, stream>>>(bufB, W2, dinv, h2t, nullptr, N);
        int tailidx = (out_size > N * OC) ? (N * OC) : -1;
        csr_agg16x2_kernel<false, false><<<g2, 256, 0, stream>>>(
            pse, srcsP, dinv, h2t, h2t, b2, outp, OC, g2, N, tailidx);
    }
}